// Round 3
// baseline (82.871 us; speedup 1.0000x reference)
//
#include <hip/hip_runtime.h>
#include <math.h>

#define BLOCK 128
#define CHUNK 8
#define SEG   (BLOCK * CHUNK)   // 1024 l-values per block
#define MAXN  64                // max supported state_dim/2 (bench uses 32)

typedef float f32x2 __attribute__((ext_vector_type(2)));

// out[h,l] = 2 * Re( sum_n C'_{hn} * w_{hn}^l ),  w = exp(dtA)
//
// Fast path (Im(dtA) uniform across modes — true when A_im is constant):
//   w_n^l = rho_n^l * e^{i*y0*l}, rho real. out[l] = 2(SR*cos - SI*sin),
//   S(l) = sum_n c'_n rho_n^l: per mode-pair-term 1 pk_mul + 2 pk_fma.
//   Modes sorted by die-length; blocks at large l break out of the pair
//   loop early (|c| rho^l < 1e-5 => truncation <= 2e-5/mode, 6.4e-4 total).
// General path: round-2 real 2nd-order recurrence on Re(c' w^l).
__global__ __launch_bounds__(BLOCK) void s4_vandermonde(
    const float* __restrict__ log_dt,
    const float* __restrict__ C_re,
    const float* __restrict__ C_im,
    const float* __restrict__ log_A_re,
    const float* __restrict__ A_im,
    float* __restrict__ out,
    int n, int L)
{
    struct __align__(16) Smem {
        // unsorted temps (general path reads these; +2 pad keeps 8B align)
        alignas(16) float t_x[MAXN + 2], t_y[MAXN + 2];
        alignas(16) float t_cr[MAXN + 2], t_ci[MAXN + 2];
        alignas(16) float t_P[MAXN + 2];                  // |W| = exp(x*BLOCK)
        alignas(16) float t_Wr[MAXN + 2], t_Wi[MAXN + 2];
        alignas(16) float t_a[MAXN + 2], t_nb[MAXN + 2];  // 2Re(W), -|W|^2
        alignas(16) float t_ld[MAXN + 2];                 // die length (l units)
        // sorted by die length, descending (fast path)
        alignas(16) float s_x[MAXN + 2], s_cr[MAXN + 2], s_ci[MAXN + 2];
        alignas(16) float s_P[MAXN + 2], s_ld[MAXN + 2];
    };
    __shared__ Smem sm;

    const int h    = blockIdx.x;
    const int base = blockIdx.y * SEG;
    const int tid  = threadIdx.x;

    // ---- phase 1: per-mode precompute into unsorted temps ----
    for (int i = tid; i < n; i += BLOCK) {
        const float dt  = __expf(log_dt[h]);
        const float Are = -__expf(log_A_re[(size_t)h * n + i]);
        const float Aim = A_im[(size_t)h * n + i];
        const float x = Are * dt;          // < 0 (decay)
        const float y = Aim * dt;

        float ex = __expf(x), sy, cy;
        __sincosf(y, &sy, &cy);
        const float er = ex * cy, ei = ex * sy;

        // c' = C * (w-1) / A
        const float numr = er - 1.0f, numi = ei;
        const float inv  = 1.0f / (Are * Are + Aim * Aim);
        const float dr = (numr * Are + numi * Aim) * inv;
        const float di = (numi * Are - numr * Aim) * inv;
        const float Cr = C_re[(size_t)h * n + i];
        const float Ci = C_im[(size_t)h * n + i];
        const float cr = Cr * dr - Ci * di;
        const float ci = Cr * di + Ci * dr;

        // W = w^BLOCK
        const float exs = __expf(x * (float)BLOCK);
        float ss, cs;
        __sincosf(y * (float)BLOCK, &ss, &cs);

        sm.t_x[i]  = x;   sm.t_y[i]  = y;
        sm.t_cr[i] = cr;  sm.t_ci[i] = ci;
        sm.t_P[i]  = exs;
        sm.t_Wr[i] = exs * cs;  sm.t_Wi[i] = exs * ss;
        sm.t_a[i]  = 2.0f * exs * cs;
        sm.t_nb[i] = -(exs * exs);
        const float mag = fabsf(cr) + fabsf(ci);
        // dead when mag*e^{x l} < 1e-5
        sm.t_ld[i] = (logf(mag + 1e-30f) + 11.513f) / fmaxf(-x, 1e-30f);
    }
    __syncthreads();

    // ---- phase 2: uniformity check + rank-sort by die length ----
    bool uni = true;
    for (int i = 1; i < n; ++i) uni = uni && (sm.t_y[i] == sm.t_y[0]);

    for (int i = tid; i < n; i += BLOCK) {
        const float ldi = sm.t_ld[i];
        int r = 0;
        for (int j = 0; j < n; ++j) {
            const float ldj = sm.t_ld[j];
            r += (ldj > ldi) || (ldj == ldi && j < i);
        }
        sm.s_x[r]  = sm.t_x[i];
        sm.s_cr[r] = sm.t_cr[i];
        sm.s_ci[r] = sm.t_ci[i];
        sm.s_P[r]  = sm.t_P[i];
        sm.s_ld[r] = ldi;
    }
    if (tid == 0 && (n & 1)) {   // pad a dead mode so pair loops are clean
        sm.s_x[n] = -1.0f; sm.s_cr[n] = 0.0f; sm.s_ci[n] = 0.0f;
        sm.s_P[n] = 0.0f;  sm.s_ld[n] = -1.0f;
        sm.t_x[n] = -1.0f; sm.t_y[n] = 0.0f;
        sm.t_cr[n] = 0.0f; sm.t_ci[n] = 0.0f;
        sm.t_Wr[n] = 0.0f; sm.t_Wi[n] = 0.0f;
        sm.t_a[n] = 0.0f;  sm.t_nb[n] = 0.0f;
    }
    __syncthreads();

    const int   l0 = base + tid;
    const float fl = (float)l0;
    const int npair = (n + 1) >> 1;
    float* o = out + (size_t)h * L + l0;

    if (uni) {
        // ---- fast path: shared rotation, real geometric per mode ----
        const float y0 = sm.t_y[0];
        f32x2 aR[CHUNK], aI[CHUNK];
#pragma unroll
        for (int j = 0; j < CHUNK; ++j) { aR[j] = (f32x2)(0.0f); aI[j] = (f32x2)(0.0f); }

        for (int p = 0; p < npair; ++p) {
            if (sm.s_ld[2 * p] <= (float)base) break;  // sorted: rest dead too
            const f32x2 c_r = ((const f32x2*)sm.s_cr)[p];
            const f32x2 c_i = ((const f32x2*)sm.s_ci)[p];
            const f32x2 P   = ((const f32x2*)sm.s_P)[p];
            const f32x2 xx  = ((const f32x2*)sm.s_x)[p];
            f32x2 g;
            g.x = __expf(xx.x * fl);
            g.y = __expf(xx.y * fl);
#pragma unroll
            for (int j = 0; j < CHUNK; ++j) {
                aR[j] = __builtin_elementwise_fma(c_r, g, aR[j]);
                aI[j] = __builtin_elementwise_fma(c_i, g, aI[j]);
                g = g * P;
            }
        }
#pragma unroll
        for (int j = 0; j < CHUNK; ++j) {
            const int l = l0 + j * BLOCK;
            float sc, cc;
            __sincosf(y0 * (float)l, &sc, &cc);
            const float SR = aR[j].x + aR[j].y;
            const float SI = aI[j].x + aI[j].y;
            if (l < L) o[(size_t)j * BLOCK] = 2.0f * (SR * cc - SI * sc);
        }
    } else {
        // ---- general path: real 2nd-order recurrence (round-2 scheme) ----
        float acc[CHUNK];
#pragma unroll
        for (int j = 0; j < CHUNK; ++j) acc[j] = 0.0f;

        const int nn = (n & 1) ? n + 1 : n;   // include pad (zero contribution)
        for (int i = 0; i < nn; ++i) {
            const float x = sm.t_x[i], y = sm.t_y[i];
            float e0 = __expf(x * fl), s0, c0;
            __sincosf(y * fl, &s0, &c0);
            const float cr = sm.t_cr[i], ci = sm.t_ci[i];
            const float sr = e0 * (cr * c0 - ci * s0);
            const float si = e0 * (cr * s0 + ci * c0);
            float rp = sr;
            float rc = sr * sm.t_Wr[i] - si * sm.t_Wi[i];
            const float a = sm.t_a[i], nb = sm.t_nb[i];
            acc[0] += rp;
            acc[1] += rc;
#pragma unroll
            for (int j = 2; j < CHUNK; ++j) {
                const float rn = fmaf(a, rc, nb * rp);
                acc[j] += rn;
                rp = rc;
                rc = rn;
            }
        }
#pragma unroll
        for (int j = 0; j < CHUNK; ++j) {
            const int l = l0 + j * BLOCK;
            if (l < L) o[(size_t)j * BLOCK] = 2.0f * acc[j];
        }
    }
}

extern "C" void kernel_launch(void* const* d_in, const int* in_sizes, int n_in,
                              void* d_out, int out_size, void* d_ws, size_t ws_size,
                              hipStream_t stream) {
    const float* log_dt   = (const float*)d_in[0];
    const float* C_re     = (const float*)d_in[1];
    const float* C_im     = (const float*)d_in[2];
    const float* log_A_re = (const float*)d_in[3];
    const float* A_im     = (const float*)d_in[4];
    float* out = (float*)d_out;

    const int H = in_sizes[0];          // 1024
    const int n = in_sizes[1] / H;      // 32
    const int L = out_size / H;         // 4096

    const int lchunks = (L + SEG - 1) / SEG;
    dim3 grid(H, lchunks);
    s4_vandermonde<<<grid, BLOCK, 0, stream>>>(
        log_dt, C_re, C_im, log_A_re, A_im, out, n, L);
}

// Round 4
// 81.507 us; speedup vs baseline: 1.0167x; 1.0167x over previous
//
#include <hip/hip_runtime.h>
#include <math.h>

#define BLOCK 128
#define CHUNK 8
#define SEG   (BLOCK * CHUNK)   // 1024 l-values per block
#define MAXN  64                // max supported state_dim/2 (bench uses 32)

typedef float f32x2 __attribute__((ext_vector_type(2)));

// out[h,l] = 2 * Re( sum_n C'_{hn} * w_{hn}^l ),  w = exp(dtA)
//
// Fast path (Im(dtA) uniform across modes — true when A_im is constant):
//   w_n^l = rho_n^l * e^{i*y0*l}, rho real. out[l] = 2(SR*cos - SI*sin),
//   S(l) = sum_n c'_n rho_n^l. Per mode-pair term: 1 pk_mul + 2 pk_fma.
// Early exit: pair skipped when both modes satisfy |c| rho^base < 1e-5
//   (block-uniform test; truncation <= 6.4e-4 total, threshold is 4.4e-2).
// General path: real 2nd-order recurrence on Re(c' w^l) (round-2 scheme),
//   same per-mode skip.
__global__ __launch_bounds__(BLOCK) void s4_vandermonde(
    const float* __restrict__ log_dt,
    const float* __restrict__ C_re,
    const float* __restrict__ C_im,
    const float* __restrict__ log_A_re,
    const float* __restrict__ A_im,
    float* __restrict__ out,
    int n, int L)
{
    struct Smem {
        alignas(16) float x[MAXN + 2], y[MAXN + 2];
        alignas(16) float cr[MAXN + 2], ci[MAXN + 2];
        alignas(16) float P[MAXN + 2];                 // |W| = exp(x*BLOCK)
        alignas(16) float Wr[MAXN + 2], Wi[MAXN + 2];  // W = w^BLOCK
        alignas(16) float a[MAXN + 2], nb[MAXN + 2];   // 2Re(W), -|W|^2
        alignas(16) float ld[MAXN + 2];                // die length (l units)
    };
    __shared__ Smem sm;

    const int h    = blockIdx.x;
    const int base = blockIdx.y * SEG;
    const int tid  = threadIdx.x;
    const int nn   = (n + 1) & ~1;       // pad odd n with a dead mode

    // ---- phase 1: per-mode precompute (one pass, first nn lanes) ----
    for (int i = tid; i < nn; i += BLOCK) {
        float x = -1.0f, y = 0.0f, cr = 0.0f, ci = 0.0f;
        float P = 0.0f, Wr = 0.0f, Wi = 0.0f, ld = -1.0f;
        if (i < n) {
            const float dt  = __expf(log_dt[h]);
            const float Are = -__expf(log_A_re[(size_t)h * n + i]);
            const float Aim = A_im[(size_t)h * n + i];
            x = Are * dt;                // < 0 (decay)
            y = Aim * dt;

            float ex = __expf(x), sy, cy;
            __sincosf(y, &sy, &cy);
            const float er = ex * cy, ei = ex * sy;

            // c' = C * (w-1) / A
            const float numr = er - 1.0f, numi = ei;
            const float inv  = 1.0f / (Are * Are + Aim * Aim);
            const float dr = (numr * Are + numi * Aim) * inv;
            const float di = (numi * Are - numr * Aim) * inv;
            const float Cr = C_re[(size_t)h * n + i];
            const float Ci = C_im[(size_t)h * n + i];
            cr = Cr * dr - Ci * di;
            ci = Cr * di + Ci * dr;

            // W = w^BLOCK
            P = __expf(x * (float)BLOCK);
            float ss, cs;
            __sincosf(y * (float)BLOCK, &ss, &cs);
            Wr = P * cs;
            Wi = P * ss;

            const float mag = fabsf(cr) + fabsf(ci);
            // dead when mag * e^{x l} < 1e-5  (log(1e-5) = -11.513)
            ld = (logf(mag + 1e-30f) + 11.513f) / fmaxf(-x, 1e-30f);
        }
        sm.x[i]  = x;   sm.y[i]  = y;
        sm.cr[i] = cr;  sm.ci[i] = ci;
        sm.P[i]  = P;
        sm.Wr[i] = Wr;  sm.Wi[i] = Wi;
        sm.a[i]  = 2.0f * Wr;
        sm.nb[i] = -(P * P);
        sm.ld[i] = ld;
    }
    __syncthreads();

    // uniformity of Im(dtA) across live modes (block-uniform result)
    bool uni = true;
    for (int i = 1; i < n; ++i) uni = uni && (sm.y[i] == sm.y[0]);

    const int   l0 = base + tid;
    const float fl = (float)l0;
    const float fbase = (float)base;
    const int npair = nn >> 1;
    float* o = out + (size_t)h * L + l0;

    if (uni) {
        // ---- fast path: shared rotation, real geometric per mode ----
        const float y0 = sm.y[0];
        f32x2 aR[CHUNK], aI[CHUNK];
#pragma unroll
        for (int j = 0; j < CHUNK; ++j) { aR[j] = (f32x2)(0.0f); aI[j] = (f32x2)(0.0f); }

        for (int p = 0; p < npair; ++p) {
            const int i0 = 2 * p;
            if (sm.ld[i0] <= fbase && sm.ld[i0 + 1] <= fbase) continue;
            const f32x2 c_r = ((const f32x2*)sm.cr)[p];
            const f32x2 c_i = ((const f32x2*)sm.ci)[p];
            const f32x2 P   = ((const f32x2*)sm.P)[p];
            const f32x2 xx  = ((const f32x2*)sm.x)[p];
            f32x2 g;
            g.x = __expf(xx.x * fl);
            g.y = __expf(xx.y * fl);
#pragma unroll
            for (int j = 0; j < CHUNK; ++j) {
                aR[j] = __builtin_elementwise_fma(c_r, g, aR[j]);
                aI[j] = __builtin_elementwise_fma(c_i, g, aI[j]);
                g = g * P;
            }
        }
#pragma unroll
        for (int j = 0; j < CHUNK; ++j) {
            const int l = l0 + j * BLOCK;
            float sc, cc;
            __sincosf(y0 * (float)l, &sc, &cc);
            const float SR = aR[j].x + aR[j].y;
            const float SI = aI[j].x + aI[j].y;
            if (l < L) o[(size_t)j * BLOCK] = 2.0f * (SR * cc - SI * sc);
        }
    } else {
        // ---- general path: real 2nd-order recurrence (round-2 scheme) ----
        float acc[CHUNK];
#pragma unroll
        for (int j = 0; j < CHUNK; ++j) acc[j] = 0.0f;

        for (int i = 0; i < nn; ++i) {
            if (sm.ld[i] <= fbase) continue;
            const float x = sm.x[i], y = sm.y[i];
            float e0 = __expf(x * fl), s0, c0;
            __sincosf(y * fl, &s0, &c0);
            const float cr = sm.cr[i], ci = sm.ci[i];
            const float sr = e0 * (cr * c0 - ci * s0);
            const float si = e0 * (cr * s0 + ci * c0);
            float rp = sr;
            float rc = sr * sm.Wr[i] - si * sm.Wi[i];
            const float a = sm.a[i], nb = sm.nb[i];
            acc[0] += rp;
            acc[1] += rc;
#pragma unroll
            for (int j = 2; j < CHUNK; ++j) {
                const float rn = fmaf(a, rc, nb * rp);
                acc[j] += rn;
                rp = rc;
                rc = rn;
            }
        }
#pragma unroll
        for (int j = 0; j < CHUNK; ++j) {
            const int l = l0 + j * BLOCK;
            if (l < L) o[(size_t)j * BLOCK] = 2.0f * acc[j];
        }
    }
}

extern "C" void kernel_launch(void* const* d_in, const int* in_sizes, int n_in,
                              void* d_out, int out_size, void* d_ws, size_t ws_size,
                              hipStream_t stream) {
    const float* log_dt   = (const float*)d_in[0];
    const float* C_re     = (const float*)d_in[1];
    const float* C_im     = (const float*)d_in[2];
    const float* log_A_re = (const float*)d_in[3];
    const float* A_im     = (const float*)d_in[4];
    float* out = (float*)d_out;

    const int H = in_sizes[0];          // 1024
    const int n = in_sizes[1] / H;      // 32
    const int L = out_size / H;         // 4096

    const int lchunks = (L + SEG - 1) / SEG;
    dim3 grid(H, lchunks);
    s4_vandermonde<<<grid, BLOCK, 0, stream>>>(
        log_dt, C_re, C_im, log_A_re, A_im, out, n, L);
}